// Round 5
// baseline (281.751 us; speedup 1.0000x reference)
//
#include <hip/hip_runtime.h>
#include <hip/hip_fp16.h>
#include <math.h>

// GCN, R15 (resubmit after infra failure): CSR build rebuilt for parallelism —
// no eb slab round-trip, no LDS counting sorts. k_deg (global atomics, full
// grid) -> k_bucket2 (per-bucket pad-scan + pad-fill + transform-first u1h) ->
// k_scatter (direct csr scatter, full grid). Fused gather kernels unchanged
// from R14 (near their per-XCD L2-duplication cold-fill floor: 45MB fetch
// ~= 6.4MB x 8 XCDs). u rows fp16, stride 32 halves = one 64B line.

#define TPB 256
#define BSH 8                 // 256 nodes per bucket
#define BNODES 256
#define CAPSH 13              // slab capacity 8192 entries/bucket
#define CAP (1 << CAPSH)

// degree count via device atomics; block 0 zeroes dummy row n of u1h/u2h.
__global__ void k_deg(const int* __restrict__ dst, int* __restrict__ deg,
                      __half* __restrict__ u1h, __half* __restrict__ u2h,
                      int E4, int E, int n) {
    int t = threadIdx.x;
    if (blockIdx.x == 0 && t < 32) {
        u1h[(size_t)n * 32 + t] = __float2half_rn(0.f);
        u2h[(size_t)n * 32 + t] = __float2half_rn(0.f);
    }
    int i = blockIdx.x * TPB + t;
    if (i >= E4) return;
    int4 d = ((const int4*)dst)[i];
    int base = i * 4;
    atomicAdd(&deg[d.x], 1);
    if (base + 1 < E) atomicAdd(&deg[d.y], 1);
    if (base + 2 < E) atomicAdd(&deg[d.z], 1);
    if (base + 3 < E) atomicAdd(&deg[d.w], 1);
}

// per bucket: pad-scan of degrees -> row_start (slab-local), cnt8, dinv,
// csr pad-fill (node id n -> zero row), transform-first u1h rows.
__global__ void k_bucket2(const int* __restrict__ deg, const float* __restrict__ x,
                          const float* __restrict__ W1,
                          int* __restrict__ csr, int* __restrict__ row_start,
                          int* __restrict__ cnt8, float* __restrict__ dinv,
                          __half* __restrict__ u1h, int n) {
    __shared__ int lscan[BNODES];
    __shared__ float ldinv[BNODES];
    __shared__ float xs[BNODES * 18];
    int b = blockIdx.x;
    int t = threadIdx.x;
    int node0 = b << BSH;
    int beg = b << CAPSH;
    int node = node0 + t;
    int v = (node < n) ? deg[node] : 0;
    int pad = (v + 7) & ~7;          // 8-aligned segments for 8-wide agg
    lscan[t] = pad;
    __syncthreads();
    for (int off = 1; off < TPB; off <<= 1) {
        int xx = (t >= off) ? lscan[t - off] : 0;
        __syncthreads();
        lscan[t] += xx;
        __syncthreads();
    }
    int pexcl = lscan[t] - pad;
    float dv = rsqrtf(1.0f + (float)v);
    ldinv[t] = dv;
    if (node < n) {
        row_start[node] = beg + pexcl;
        cnt8[node] = pad >> 3;
        dinv[node] = dv;
    }
    for (int p = v; p < pad; ++p) csr[beg + pexcl + p] = n;
    // ---- transform-first: u1h[node][f] = ((x[node] @ W1)[f]) * dinv[node] ----
    int nn = min(BNODES, n - node0);
    const float* xb = x + (size_t)node0 * 18;
    int tot18 = nn * 18;
    for (int i = t; i < tot18; i += TPB) xs[i] = xb[i];   // coalesced stage
    __syncthreads();
    int f = t & 31, g = t >> 5;
    float w1r[18];
#pragma unroll
    for (int k = 0; k < 18; ++k) w1r[k] = W1[k * 32 + f];
    __half* ub = u1h + (size_t)node0 * 32;
    for (int nl = g; nl < nn; nl += 8) {
        const float* rp = &xs[nl * 18];
        float a = 0.f;
#pragma unroll
        for (int k = 0; k < 18; ++k) a = fmaf(rp[k], w1r[k], a);
        ub[nl * 32 + f] = __float2half_rn(a * ldinv[nl]);
    }
}

// direct scatter into final csr segments via per-node cursors.
__global__ void k_scatter(const int* __restrict__ src, const int* __restrict__ dst,
                          const int* __restrict__ row_start, int* __restrict__ cursor,
                          int* __restrict__ csr, int E4, int E) {
    int i = blockIdx.x * TPB + threadIdx.x;
    if (i >= E4) return;
    int4 d = ((const int4*)dst)[i];
    int4 s = ((const int4*)src)[i];
    int base = i * 4;
    #define SC(c, sv) if (base + c < E) { \
        int dd = d.sv; \
        int r = atomicAdd(&cursor[dd], 1); \
        csr[row_start[dd] + r] = s.sv; }
    SC(0, x) SC(1, y) SC(2, z) SC(3, w)
    #undef SC
}

// convert one gathered uint2 (4 halves) into 4 floats
#define CVT4(vv, r0, r1, r2, r3) \
    { __half2* _p = (__half2*)&(vv); \
      float2 _fl = __half22float2(_p[0]), _fh = __half22float2(_p[1]); \
      r0 = _fl.x; r1 = _fl.y; r2 = _fh.x; r3 = _fh.y; }

// gather 8 rows (sA,sB) at lane q; 2-level packed-fp16 pairwise tree
// (v_pk_add_f16), then convert and add into f32 carry accumulators.
#define GATHER8H(uq, sA, sB, q, a0, a1, a2, a3) \
    { uint2 _v0 = uq[(size_t)(sA).x * 8 + (q)]; \
      uint2 _v1 = uq[(size_t)(sA).y * 8 + (q)]; \
      uint2 _v2 = uq[(size_t)(sA).z * 8 + (q)]; \
      uint2 _v3 = uq[(size_t)(sA).w * 8 + (q)]; \
      uint2 _v4 = uq[(size_t)(sB).x * 8 + (q)]; \
      uint2 _v5 = uq[(size_t)(sB).y * 8 + (q)]; \
      uint2 _v6 = uq[(size_t)(sB).z * 8 + (q)]; \
      uint2 _v7 = uq[(size_t)(sB).w * 8 + (q)]; \
      __half2* _h0 = (__half2*)&_v0; __half2* _h1 = (__half2*)&_v1; \
      __half2* _h2 = (__half2*)&_v2; __half2* _h3 = (__half2*)&_v3; \
      __half2* _h4 = (__half2*)&_v4; __half2* _h5 = (__half2*)&_v5; \
      __half2* _h6 = (__half2*)&_v6; __half2* _h7 = (__half2*)&_v7; \
      __half2 _A01 = __hadd2(_h0[0], _h1[0]), _A23 = __hadd2(_h2[0], _h3[0]); \
      __half2 _A45 = __hadd2(_h4[0], _h5[0]), _A67 = __hadd2(_h6[0], _h7[0]); \
      __half2 _B01 = __hadd2(_h0[1], _h1[1]), _B23 = __hadd2(_h2[1], _h3[1]); \
      __half2 _B45 = __hadd2(_h4[1], _h5[1]), _B67 = __hadd2(_h6[1], _h7[1]); \
      __half2 _A03 = __hadd2(_A01, _A23), _A47 = __hadd2(_A45, _A67); \
      __half2 _B03 = __hadd2(_B01, _B23), _B47 = __hadd2(_B45, _B67); \
      float2 _fa0 = __half22float2(_A03), _fa1 = __half22float2(_A47); \
      float2 _fb0 = __half22float2(_B03), _fb1 = __half22float2(_B47); \
      a0 += _fa0.x + _fa1.x; \
      a1 += _fa0.y + _fa1.y; \
      a2 += _fb0.x + _fb1.x; \
      a3 += _fb0.y + _fb1.y; }

// fused layer1: pure aggregation (8 lanes/node, 8 rows/iter, csr prefetch)
// -> elementwise relu/scale -> u2h fp16 rows. No LDS, no transform.
__global__ void k_fused1(const uint2* __restrict__ u1q, const int* __restrict__ row_start,
                         const int* __restrict__ cnt8, const int* __restrict__ csr,
                         const float* __restrict__ dinv,
                         const float* __restrict__ b1, __half* __restrict__ u2h,
                         int n) {
    int t = threadIdx.x;
    int lane = t & 63, wv = t >> 6;
    int q = lane & 7, grp = lane >> 3;
    int node = (blockIdx.x * 4 + wv) * 8 + grp;
    if (node >= n) return;
    float4 bb = ((const float4*)b1)[q];
    uint2 sv = u1q[(size_t)node * 8 + q];
    float a0, a1, a2, a3;
    CVT4(sv, a0, a1, a2, a3)
    int beg = row_start[node];
    int it = cnt8[node];
    const int4* ip = (const int4*)(csr + beg);
    if (it > 0) {
        int4 sA = ip[0], sB = ip[1];
        for (int i = 0; i < it; ++i) {
            int4 nA = ip[2 * i + 2];          // 1-deep prefetch (slab slack)
            int4 nB = ip[2 * i + 3];
            GATHER8H(u1q, sA, sB, q, a0, a1, a2, a3)
            sA = nA; sB = nB;
        }
    }
    float di = dinv[node];
    float r0 = fmaxf(fmaf(di, a0, bb.x), 0.f) * di;
    float r1 = fmaxf(fmaf(di, a1, bb.y), 0.f) * di;
    float r2 = fmaxf(fmaf(di, a2, bb.z), 0.f) * di;
    float r3 = fmaxf(fmaf(di, a3, bb.w), 0.f) * di;
    uint2 st;
    __half2* sp = (__half2*)&st;
    sp[0].x = __float2half_rn(r0); sp[0].y = __float2half_rn(r1);
    sp[1].x = __float2half_rn(r2); sp[1].y = __float2half_rn(r3);
    ((uint2*)u2h)[(size_t)node * 8 + q] = st;
}

// fused layer2 + head: agg (8 lanes/node, 8 rows/iter) -> intra-wave LDS ->
// transform (lane = output o, W2 col in 32 VGPRs) -> FC(64->2) butterfly
// -> log_softmax.
__global__ void k_fused2(const uint2* __restrict__ u2q, const int* __restrict__ row_start,
                         const int* __restrict__ cnt8, const int* __restrict__ csr,
                         const float* __restrict__ dinv,
                         const float* __restrict__ W2,
                         const float* __restrict__ b2, const float* __restrict__ Wfc,
                         const float* __restrict__ bfc, float* __restrict__ out,
                         int n) {
    __shared__ float lagg[4][8][33];
    int t = threadIdx.x;
    int lane = t & 63, wv = t >> 6;
    int q = lane & 7, grp = lane >> 3;
    float w2r[32];
#pragma unroll
    for (int k = 0; k < 32; ++k) w2r[k] = W2[k * 64 + lane];
    float b2v = b2[lane];
    float wf0 = Wfc[lane * 2 + 0], wf1 = Wfc[lane * 2 + 1];
    float bf0 = bfc[0], bf1 = bfc[1];
    int node0 = (blockIdx.x * 4 + wv) * 8;
    int node = node0 + grp;
    float a0 = 0.f, a1 = 0.f, a2 = 0.f, a3 = 0.f;
    if (node < n) {
        uint2 sv = u2q[(size_t)node * 8 + q];
        float s0, s1, s2, s3;
        CVT4(sv, s0, s1, s2, s3)
        a0 = s0; a1 = s1; a2 = s2; a3 = s3;
        int beg = row_start[node];
        int it = cnt8[node];
        const int4* ip = (const int4*)(csr + beg);
        if (it > 0) {
            int4 sA = ip[0], sB = ip[1];
            for (int i = 0; i < it; ++i) {
                int4 nA = ip[2 * i + 2];      // 1-deep prefetch
                int4 nB = ip[2 * i + 3];
                GATHER8H(u2q, sA, sB, q, a0, a1, a2, a3)
                sA = nA; sB = nB;
            }
        }
    }
    lagg[wv][grp][4 * q + 0] = a0;
    lagg[wv][grp][4 * q + 1] = a1;
    lagg[wv][grp][4 * q + 2] = a2;
    lagg[wv][grp][4 * q + 3] = a3;
#pragma unroll
    for (int r = 0; r < 8; ++r) {
        int nodeT = node0 + r;
        const float* rp = lagg[wv][r];
        float c0 = 0.f, c1 = 0.f, c2 = 0.f, c3 = 0.f;
#pragma unroll
        for (int k = 0; k < 32; k += 4) {
            c0 = fmaf(rp[k],     w2r[k],     c0);
            c1 = fmaf(rp[k + 1], w2r[k + 1], c1);
            c2 = fmaf(rp[k + 2], w2r[k + 2], c2);
            c3 = fmaf(rp[k + 3], w2r[k + 3], c3);
        }
        float a = (c0 + c1) + (c2 + c3);
        float v = (nodeT < n) ? fmaxf(fmaf(dinv[nodeT], a, b2v), 0.f) : 0.f;
        float l0 = v * wf0;
        float l1 = v * wf1;
#pragma unroll
        for (int off = 32; off >= 1; off >>= 1) {
            l0 += __shfl_xor(l0, off, 64);
            l1 += __shfl_xor(l1, off, 64);
        }
        if (lane == 0 && nodeT < n) {
            l0 += bf0;
            l1 += bf1;
            float m2 = fmaxf(l0, l1);
            float lse = m2 + logf(expf(l0 - m2) + expf(l1 - m2));
            out[nodeT * 2 + 0] = l0 - lse;
            out[nodeT * 2 + 1] = l1 - lse;
        }
    }
}

extern "C" void kernel_launch(void* const* d_in, const int* in_sizes, int n_in,
                              void* d_out, int out_size, void* d_ws, size_t ws_size,
                              hipStream_t stream) {
    const float* x   = (const float*)d_in[0];
    const int*   ei  = (const int*)d_in[1];
    const float* W1  = (const float*)d_in[2];
    const float* b1  = (const float*)d_in[3];
    const float* W2  = (const float*)d_in[4];
    const float* b2  = (const float*)d_in[5];
    const float* Wfc = (const float*)d_in[6];
    const float* bfc = (const float*)d_in[7];
    float* out = (float*)d_out;

    const int n = in_sizes[0] / 18;
    const int E = in_sizes[1] / 2;
    const int* src = ei;
    const int* dst = ei + E;
    const int nbuck = (n + BNODES - 1) >> BSH;

    // ws: deg[n] | cursor[n] (one memset) | row_start[n] | cnt8[n] | dinv[n]
    //  | csr[nbuck*CAP]+slack | u1h[(n+1)*32 h] | u2h[(n+1)*32 h]
    char* w = (char*)d_ws;
    int*    deg       = (int*)w;     w += (size_t)n * 4;
    int*    cursor    = (int*)w;     w += (size_t)n * 4;
    int*    row_start = (int*)w;     w += (size_t)n * 4;
    int*    cnt8      = (int*)w;     w += (size_t)n * 4;
    float*  dinv      = (float*)w;   w += (size_t)n * 4;
    int*    csr       = (int*)w;     w += (size_t)nbuck * CAP * 4 + 64;  // +prefetch slack
    w = (char*)(((size_t)w + 63) & ~(size_t)63);
    __half* u1h       = (__half*)w;  w += (size_t)(n + 1) * 32 * 2;
    w = (char*)(((size_t)w + 63) & ~(size_t)63);
    __half* u2h       = (__half*)w;  w += (size_t)(n + 1) * 32 * 2;

    // ---- CSR build: deg atomics -> per-bucket pad-scan -> direct scatter ----
    hipMemsetAsync(deg, 0, (size_t)2 * n * 4, stream);   // deg + cursor
    const int E4 = (E + 3) / 4;
    const int edgeBlocks = (E4 + TPB - 1) / TPB;
    k_deg<<<edgeBlocks, TPB, 0, stream>>>(dst, deg, u1h, u2h, E4, E, n);
    k_bucket2<<<nbuck, TPB, 0, stream>>>(deg, x, W1, csr, row_start, cnt8,
                                         dinv, u1h, n);
    k_scatter<<<edgeBlocks, TPB, 0, stream>>>(src, dst, row_start, cursor, csr, E4, E);

    const int waves = (n + 7) / 8;
    const int blocksF = (waves + 3) / 4;

    k_fused1<<<blocksF, TPB, 0, stream>>>((const uint2*)u1h, row_start, cnt8, csr,
                                          dinv, b1, u2h, n);
    k_fused2<<<blocksF, TPB, 0, stream>>>((const uint2*)u2h, row_start, cnt8, csr,
                                          dinv, W2, b2, Wfc, bfc, out, n);
}

// Round 6
// 169.350 us; speedup vs baseline: 1.6637x; 1.6637x over previous
//
#include <hip/hip_runtime.h>
#include <hip/hip_fp16.h>
#include <math.h>

// GCN, R16: best-of recombination. k_part = R13 direct-atomic slab writes
// (per-bucket cursor makes same-bucket edges land contiguously -> L2 merges;
// no LDS chunk sort, which cost +8us in R14). CH=4096 for 313-block grid.
// k_bucket = counting sort into padded csr segments + transform-first u1h.
// Fused kernels = R14 pk-fp16 pairwise-tree aggregation (proven -7us+).
// u rows fp16, stride 32 halves = one 64B line. eb packed (src<<8)|(dst&255).

#define TPB 256
#define BSH 8                 // 256 nodes per bucket
#define BNODES 256
#define MAXBUCK 512
#define CH 4096               // edges per partition block
#define CAPSH 13              // slab capacity 8192 entries/bucket
#define CAP (1 << CAPSH)

// partition edges into per-bucket slabs; bcursor RELATIVE (memset 0).
// block 0 also zeroes the dummy row n of u1h/u2h.
__global__ void k_part(const int* __restrict__ src, const int* __restrict__ dst,
                       int* __restrict__ bcursor, int* __restrict__ eb,
                       __half* __restrict__ u1h, __half* __restrict__ u2h,
                       int E, int n, int nbuck) {
    __shared__ int lh[MAXBUCK];
    __shared__ int lbase[MAXBUCK];
    int t = threadIdx.x;
    if (blockIdx.x == 0 && t < 32) {
        u1h[(size_t)n * 32 + t] = __float2half_rn(0.f);
        u2h[(size_t)n * 32 + t] = __float2half_rn(0.f);
    }
    int chunk0 = blockIdx.x * CH;
    int end = min(chunk0 + CH, E);
    const int4* dst4 = (const int4*)dst;
    const int4* src4 = (const int4*)src;
    for (int i = t; i < nbuck; i += TPB) lh[i] = 0;
    __syncthreads();
    for (int e4 = chunk0 / 4 + t; e4 * 4 < end; e4 += TPB) {
        int base = e4 * 4;
        int4 d = dst4[e4];
        if (base + 0 < end) atomicAdd(&lh[d.x >> BSH], 1);
        if (base + 1 < end) atomicAdd(&lh[d.y >> BSH], 1);
        if (base + 2 < end) atomicAdd(&lh[d.z >> BSH], 1);
        if (base + 3 < end) atomicAdd(&lh[d.w >> BSH], 1);
    }
    __syncthreads();
    for (int i = t; i < nbuck; i += TPB) {
        int c = lh[i];
        lbase[i] = c ? atomicAdd(&bcursor[i], c) : 0;
        lh[i] = 0;
    }
    __syncthreads();
    for (int e4 = chunk0 / 4 + t; e4 * 4 < end; e4 += TPB) {
        int base = e4 * 4;
        int4 d = dst4[e4];
        int4 s = src4[e4];
        #define PUT(c, sv) if (base + c < end) { \
            int b = (d.sv) >> BSH; \
            int r = lbase[b] + atomicAdd(&lh[b], 1); \
            if (r < CAP) \
                eb[((size_t)b << CAPSH) + r] = ((s.sv) << BSH) | ((d.sv) & (BNODES - 1)); }
        PUT(0, x) PUT(1, y) PUT(2, z) PUT(3, w)
        #undef PUT
    }
}

// per bucket: LDS counting sort into PADDED csr segments (8-aligned starts,
// pads = node id n -> zero row). Outputs row_start, cnt8, dinv, and
// transform-first u1h rows: (x@W1)*dinv in fp16.
__global__ void k_bucket(const int* __restrict__ eb, const int* __restrict__ bcursor,
                         const float* __restrict__ x, const float* __restrict__ W1,
                         int* __restrict__ csr, int* __restrict__ row_start,
                         int* __restrict__ cnt8, float* __restrict__ dinv,
                         __half* __restrict__ u1h, int n) {
    __shared__ int lcnt[BNODES];
    __shared__ int lscan[BNODES];
    __shared__ float ldinv[BNODES];
    __shared__ float xs[BNODES * 18];
    int b = blockIdx.x;
    int t = threadIdx.x;
    int node0 = b << BSH;
    int beg = b << CAPSH;
    int end = beg + min(bcursor[b], CAP);
    lcnt[t] = 0;
    __syncthreads();
    for (int i = beg + t; i < end; i += TPB)
        atomicAdd(&lcnt[eb[i] & (BNODES - 1)], 1);
    __syncthreads();
    int v = lcnt[t];
    int pad = (v + 7) & ~7;          // 8-aligned segments for 8-wide agg
    lscan[t] = pad;
    __syncthreads();
    for (int off = 1; off < TPB; off <<= 1) {
        int xx = (t >= off) ? lscan[t - off] : 0;
        __syncthreads();
        lscan[t] += xx;
        __syncthreads();
    }
    int pexcl = lscan[t] - pad;
    int node = node0 + t;
    float dv = rsqrtf(1.0f + (float)v);
    ldinv[t] = dv;
    if (node < n) {
        row_start[node] = beg + pexcl;
        cnt8[node] = pad >> 3;
        dinv[node] = dv;
    }
    __syncthreads();
    lcnt[t] = pexcl;
    __syncthreads();
    for (int i = beg + t; i < end; i += TPB) {
        int e = eb[i];
        int p = atomicAdd(&lcnt[e & (BNODES - 1)], 1);
        csr[beg + p] = e >> BSH;
    }
    __syncthreads();
    for (int p = v; p < pad; ++p) csr[beg + pexcl + p] = n;
    // ---- transform-first: u1h[node][f] = ((x[node] @ W1)[f]) * dinv[node] ----
    int nn = min(BNODES, n - node0);
    const float* xb = x + (size_t)node0 * 18;
    int tot18 = nn * 18;
    for (int i = t; i < tot18; i += TPB) xs[i] = xb[i];   // coalesced stage
    __syncthreads();
    int f = t & 31, g = t >> 5;
    float w1r[18];
#pragma unroll
    for (int k = 0; k < 18; ++k) w1r[k] = W1[k * 32 + f];
    __half* ub = u1h + (size_t)node0 * 32;
    for (int nl = g; nl < nn; nl += 8) {
        const float* rp = &xs[nl * 18];
        float a = 0.f;
#pragma unroll
        for (int k = 0; k < 18; ++k) a = fmaf(rp[k], w1r[k], a);
        ub[nl * 32 + f] = __float2half_rn(a * ldinv[nl]);
    }
}

// convert one gathered uint2 (4 halves) into 4 floats
#define CVT4(vv, r0, r1, r2, r3) \
    { __half2* _p = (__half2*)&(vv); \
      float2 _fl = __half22float2(_p[0]), _fh = __half22float2(_p[1]); \
      r0 = _fl.x; r1 = _fl.y; r2 = _fh.x; r3 = _fh.y; }

// gather 8 rows (sA,sB) at lane q; 2-level packed-fp16 pairwise tree
// (v_pk_add_f16), then convert and add into f32 carry accumulators.
#define GATHER8H(uq, sA, sB, q, a0, a1, a2, a3) \
    { uint2 _v0 = uq[(size_t)(sA).x * 8 + (q)]; \
      uint2 _v1 = uq[(size_t)(sA).y * 8 + (q)]; \
      uint2 _v2 = uq[(size_t)(sA).z * 8 + (q)]; \
      uint2 _v3 = uq[(size_t)(sA).w * 8 + (q)]; \
      uint2 _v4 = uq[(size_t)(sB).x * 8 + (q)]; \
      uint2 _v5 = uq[(size_t)(sB).y * 8 + (q)]; \
      uint2 _v6 = uq[(size_t)(sB).z * 8 + (q)]; \
      uint2 _v7 = uq[(size_t)(sB).w * 8 + (q)]; \
      __half2* _h0 = (__half2*)&_v0; __half2* _h1 = (__half2*)&_v1; \
      __half2* _h2 = (__half2*)&_v2; __half2* _h3 = (__half2*)&_v3; \
      __half2* _h4 = (__half2*)&_v4; __half2* _h5 = (__half2*)&_v5; \
      __half2* _h6 = (__half2*)&_v6; __half2* _h7 = (__half2*)&_v7; \
      __half2 _A01 = __hadd2(_h0[0], _h1[0]), _A23 = __hadd2(_h2[0], _h3[0]); \
      __half2 _A45 = __hadd2(_h4[0], _h5[0]), _A67 = __hadd2(_h6[0], _h7[0]); \
      __half2 _B01 = __hadd2(_h0[1], _h1[1]), _B23 = __hadd2(_h2[1], _h3[1]); \
      __half2 _B45 = __hadd2(_h4[1], _h5[1]), _B67 = __hadd2(_h6[1], _h7[1]); \
      __half2 _A03 = __hadd2(_A01, _A23), _A47 = __hadd2(_A45, _A67); \
      __half2 _B03 = __hadd2(_B01, _B23), _B47 = __hadd2(_B45, _B67); \
      float2 _fa0 = __half22float2(_A03), _fa1 = __half22float2(_A47); \
      float2 _fb0 = __half22float2(_B03), _fb1 = __half22float2(_B47); \
      a0 += _fa0.x + _fa1.x; \
      a1 += _fa0.y + _fa1.y; \
      a2 += _fb0.x + _fb1.x; \
      a3 += _fb0.y + _fb1.y; }

// fused layer1: pure aggregation (8 lanes/node, 8 rows/iter, csr prefetch)
// -> elementwise relu/scale -> u2h fp16 rows. No LDS, no transform.
__global__ void k_fused1(const uint2* __restrict__ u1q, const int* __restrict__ row_start,
                         const int* __restrict__ cnt8, const int* __restrict__ csr,
                         const float* __restrict__ dinv,
                         const float* __restrict__ b1, __half* __restrict__ u2h,
                         int n) {
    int t = threadIdx.x;
    int lane = t & 63, wv = t >> 6;
    int q = lane & 7, grp = lane >> 3;
    int node = (blockIdx.x * 4 + wv) * 8 + grp;
    if (node >= n) return;
    float4 bb = ((const float4*)b1)[q];
    uint2 sv = u1q[(size_t)node * 8 + q];
    float a0, a1, a2, a3;
    CVT4(sv, a0, a1, a2, a3)
    int beg = row_start[node];
    int it = cnt8[node];
    const int4* ip = (const int4*)(csr + beg);
    if (it > 0) {
        int4 sA = ip[0], sB = ip[1];
        for (int i = 0; i < it; ++i) {
            int4 nA = ip[2 * i + 2];          // 1-deep prefetch (slab slack)
            int4 nB = ip[2 * i + 3];
            GATHER8H(u1q, sA, sB, q, a0, a1, a2, a3)
            sA = nA; sB = nB;
        }
    }
    float di = dinv[node];
    float r0 = fmaxf(fmaf(di, a0, bb.x), 0.f) * di;
    float r1 = fmaxf(fmaf(di, a1, bb.y), 0.f) * di;
    float r2 = fmaxf(fmaf(di, a2, bb.z), 0.f) * di;
    float r3 = fmaxf(fmaf(di, a3, bb.w), 0.f) * di;
    uint2 st;
    __half2* sp = (__half2*)&st;
    sp[0].x = __float2half_rn(r0); sp[0].y = __float2half_rn(r1);
    sp[1].x = __float2half_rn(r2); sp[1].y = __float2half_rn(r3);
    ((uint2*)u2h)[(size_t)node * 8 + q] = st;
}

// fused layer2 + head: agg (8 lanes/node, 8 rows/iter) -> intra-wave LDS ->
// transform (lane = output o, W2 col in 32 VGPRs) -> FC(64->2) butterfly
// -> log_softmax.
__global__ void k_fused2(const uint2* __restrict__ u2q, const int* __restrict__ row_start,
                         const int* __restrict__ cnt8, const int* __restrict__ csr,
                         const float* __restrict__ dinv,
                         const float* __restrict__ W2,
                         const float* __restrict__ b2, const float* __restrict__ Wfc,
                         const float* __restrict__ bfc, float* __restrict__ out,
                         int n) {
    __shared__ float lagg[4][8][33];
    int t = threadIdx.x;
    int lane = t & 63, wv = t >> 6;
    int q = lane & 7, grp = lane >> 3;
    float w2r[32];
#pragma unroll
    for (int k = 0; k < 32; ++k) w2r[k] = W2[k * 64 + lane];
    float b2v = b2[lane];
    float wf0 = Wfc[lane * 2 + 0], wf1 = Wfc[lane * 2 + 1];
    float bf0 = bfc[0], bf1 = bfc[1];
    int node0 = (blockIdx.x * 4 + wv) * 8;
    int node = node0 + grp;
    float a0 = 0.f, a1 = 0.f, a2 = 0.f, a3 = 0.f;
    if (node < n) {
        uint2 sv = u2q[(size_t)node * 8 + q];
        float s0, s1, s2, s3;
        CVT4(sv, s0, s1, s2, s3)
        a0 = s0; a1 = s1; a2 = s2; a3 = s3;
        int beg = row_start[node];
        int it = cnt8[node];
        const int4* ip = (const int4*)(csr + beg);
        if (it > 0) {
            int4 sA = ip[0], sB = ip[1];
            for (int i = 0; i < it; ++i) {
                int4 nA = ip[2 * i + 2];      // 1-deep prefetch
                int4 nB = ip[2 * i + 3];
                GATHER8H(u2q, sA, sB, q, a0, a1, a2, a3)
                sA = nA; sB = nB;
            }
        }
    }
    lagg[wv][grp][4 * q + 0] = a0;
    lagg[wv][grp][4 * q + 1] = a1;
    lagg[wv][grp][4 * q + 2] = a2;
    lagg[wv][grp][4 * q + 3] = a3;
#pragma unroll
    for (int r = 0; r < 8; ++r) {
        int nodeT = node0 + r;
        const float* rp = lagg[wv][r];
        float c0 = 0.f, c1 = 0.f, c2 = 0.f, c3 = 0.f;
#pragma unroll
        for (int k = 0; k < 32; k += 4) {
            c0 = fmaf(rp[k],     w2r[k],     c0);
            c1 = fmaf(rp[k + 1], w2r[k + 1], c1);
            c2 = fmaf(rp[k + 2], w2r[k + 2], c2);
            c3 = fmaf(rp[k + 3], w2r[k + 3], c3);
        }
        float a = (c0 + c1) + (c2 + c3);
        float v = (nodeT < n) ? fmaxf(fmaf(dinv[nodeT], a, b2v), 0.f) : 0.f;
        float l0 = v * wf0;
        float l1 = v * wf1;
#pragma unroll
        for (int off = 32; off >= 1; off >>= 1) {
            l0 += __shfl_xor(l0, off, 64);
            l1 += __shfl_xor(l1, off, 64);
        }
        if (lane == 0 && nodeT < n) {
            l0 += bf0;
            l1 += bf1;
            float m2 = fmaxf(l0, l1);
            float lse = m2 + logf(expf(l0 - m2) + expf(l1 - m2));
            out[nodeT * 2 + 0] = l0 - lse;
            out[nodeT * 2 + 1] = l1 - lse;
        }
    }
}

extern "C" void kernel_launch(void* const* d_in, const int* in_sizes, int n_in,
                              void* d_out, int out_size, void* d_ws, size_t ws_size,
                              hipStream_t stream) {
    const float* x   = (const float*)d_in[0];
    const int*   ei  = (const int*)d_in[1];
    const float* W1  = (const float*)d_in[2];
    const float* b1  = (const float*)d_in[3];
    const float* W2  = (const float*)d_in[4];
    const float* b2  = (const float*)d_in[5];
    const float* Wfc = (const float*)d_in[6];
    const float* bfc = (const float*)d_in[7];
    float* out = (float*)d_out;

    const int n = in_sizes[0] / 18;
    const int E = in_sizes[1] / 2;
    const int* src = ei;
    const int* dst = ei + E;
    const int nbuck = (n + BNODES - 1) >> BSH;

    // ws: bcursor[nbuck] | row_start[n] | cnt8[n] | dinv[n]
    //  | eb[nbuck*CAP] | csr[nbuck*CAP]+slack | u1h[(n+1)*32 h] | u2h[(n+1)*32 h]
    char* w = (char*)d_ws;
    int*    bcursor   = (int*)w;     w += (size_t)nbuck * 4;
    int*    row_start = (int*)w;     w += (size_t)n * 4;
    int*    cnt8      = (int*)w;     w += (size_t)n * 4;
    float*  dinv      = (float*)w;   w += (size_t)n * 4;
    int*    eb        = (int*)w;     w += (size_t)nbuck * CAP * 4;
    int*    csr       = (int*)w;     w += (size_t)nbuck * CAP * 4 + 64;  // +prefetch slack
    w = (char*)(((size_t)w + 63) & ~(size_t)63);
    __half* u1h       = (__half*)w;  w += (size_t)(n + 1) * 32 * 2;
    w = (char*)(((size_t)w + 63) & ~(size_t)63);
    __half* u2h       = (__half*)w;  w += (size_t)(n + 1) * 32 * 2;

    // ---- CSR build: slab bucket sort with padded segments ----
    hipMemsetAsync(bcursor, 0, (size_t)nbuck * 4, stream);
    k_part<<<(E + CH - 1) / CH, TPB, 0, stream>>>(src, dst, bcursor, eb, u1h, u2h, E, n, nbuck);
    k_bucket<<<nbuck, TPB, 0, stream>>>(eb, bcursor, x, W1, csr, row_start, cnt8,
                                        dinv, u1h, n);

    const int waves = (n + 7) / 8;
    const int blocksF = (waves + 3) / 4;

    k_fused1<<<blocksF, TPB, 0, stream>>>((const uint2*)u1h, row_start, cnt8, csr,
                                          dinv, b1, u2h, n);
    k_fused2<<<blocksF, TPB, 0, stream>>>((const uint2*)u2h, row_start, cnt8, csr,
                                          dinv, W2, b2, Wfc, bfc, out, n);
}